// Round 3
// baseline (743.780 us; speedup 1.0000x reference)
//
#include <hip/hip_runtime.h>
#include <hip/hip_bf16.h>
#include <cstdint>

// ---------- types ----------
typedef __attribute__((ext_vector_type(4))) float f32x4;
typedef __attribute__((ext_vector_type(8))) short bf16x8;   // 8 bf16 = 4 VGPRs
typedef __attribute__((ext_vector_type(4))) short s16x4;
typedef __attribute__((ext_vector_type(8))) short s16x8;

// fp32 -> bf16 round-to-nearest-even (inputs are finite; no NaN path needed)
__device__ __forceinline__ short f2bf(float f) {
    union { float f; unsigned u; } v; v.f = f;
    unsigned r = v.u + 0x7FFFu + ((v.u >> 16) & 1u);
    return (short)(r >> 16);
}

__device__ __forceinline__ float gelu_exact(float v) {
    return 0.5f * v * (1.0f + erff(v * 0.70710678118654752f));
}

// ---------- merged prep: cast x, transpose+cast wi and wo ----------
// blocks [0,8192): cast x (2048 elems/block)
// blocks [8192,16384): wi [E][1024][4096] -> wiT [E][4096][1024]
// blocks [16384,24576): wo [E][4096][1024] -> woT [E][1024][4096]
__global__ __launch_bounds__(256) void prep(const float* __restrict__ x,
                                            const float* __restrict__ wi,
                                            const float* __restrict__ wo,
                                            short* __restrict__ xb,
                                            short* __restrict__ wiT,
                                            short* __restrict__ woT) {
    __shared__ float t[64][65];                 // +1 pad
    const int b = blockIdx.x, tid = threadIdx.x;
    if (b < 8192) {                             // ---- cast path ----
        const long i = ((long)b * 256 + tid) * 8;
        float4 a = *(const float4*)(x + i);
        float4 c = *(const float4*)(x + i + 4);
        s16x8 o;
        o[0] = f2bf(a.x); o[1] = f2bf(a.y); o[2] = f2bf(a.z); o[3] = f2bf(a.w);
        o[4] = f2bf(c.x); o[5] = f2bf(c.y); o[6] = f2bf(c.z); o[7] = f2bf(c.w);
        *(s16x8*)(xb + i) = o;
        return;
    }
    // ---- transpose path: in fp32 [R][C] -> out bf16 [C][R], 64x64 tile ----
    const float* in; short* out; int R, C, c0, r0;
    if (b < 16384) {
        const int b2 = b - 8192, e = b2 >> 10, tt = b2 & 1023;
        R = 1024; C = 4096;
        c0 = (tt & 63) * 64; r0 = (tt >> 6) * 64;
        in  = wi  + (size_t)e * R * C;
        out = wiT + (size_t)e * R * C;
    } else {
        const int b3 = b - 16384, e = b3 >> 10, tt = b3 & 1023;
        R = 4096; C = 1024;
        c0 = (tt & 15) * 64; r0 = (tt >> 4) * 64;
        in  = wo  + (size_t)e * R * C;
        out = woT + (size_t)e * R * C;
    }
    const int lr = tid >> 4, lc4 = (tid & 15) * 4;
    #pragma unroll
    for (int i = 0; i < 4; ++i) {
        const int row = i * 16 + lr;
        float4 v = *(const float4*)(in + (size_t)(r0 + row) * C + c0 + lc4);
        t[row][lc4 + 0] = v.x; t[row][lc4 + 1] = v.y;
        t[row][lc4 + 2] = v.z; t[row][lc4 + 3] = v.w;
    }
    __syncthreads();
    const int rseg = (tid & 7) * 8;             // 8 consecutive out elements
    #pragma unroll
    for (int i = 0; i < 2; ++i) {
        const int oc = i * 32 + (tid >> 3);     // output row (= input col)
        s16x8 o;
        #pragma unroll
        for (int j = 0; j < 8; ++j) o[j] = f2bf(t[rseg + j][oc]);
        *(s16x8*)(out + (size_t)(c0 + oc) * R + r0 + rseg) = o;   // 16B store
    }
}

// ---------- async global -> LDS staging of a 128x64 bf16 tile ----------
// LDS flat [row][8 x 16B chunks], chunk slot XOR-swizzled by (row&7);
// swizzle applied on the GLOBAL address (LDS dest must be lane-linear).
__device__ __forceinline__ void stage_tile64(const short* __restrict__ g,
                                             short* lds, int ld,
                                             int wave, int lane) {
    #pragma unroll
    for (int i = 0; i < 4; ++i) {
        const int c    = i * 256 + wave * 64 + lane;   // 16B chunk id, 0..1023
        const int row  = c >> 3;
        const int slot = c & 7;
        const int gkc  = (slot ^ (row & 7)) << 3;      // global k-offset (shorts)
        const short* gp = g + (size_t)row * ld + gkc;
        short* lp = lds + (size_t)(i * 256 + wave * 64) * 8;  // wave-uniform base
        __builtin_amdgcn_global_load_lds(
            (const __attribute__((address_space(1))) void*)gp,
            (__attribute__((address_space(3))) void*)lp, 16, 0, 0);
    }
}

// ---------- GEMM: C[e] = A[e] (MxK row-major) * Bt[e]^T (Bt NxK row-major)
// FUSE=1 (GEMM1): 1-D grid, expert = bid&7 (XCD-pinned), col-band-of-4 order,
//                 gelu + bf16 out.    Mt=16, Nt=32 hardcoded.
// FUSE=0 (GEMM2): 3-D grid, band-of-4 M x sweep N, fp32 out.
template <int FUSE>
__global__ __launch_bounds__(256) void gemm_bt(const short* __restrict__ A,
                                               const short* __restrict__ Bt,
                                               void* __restrict__ Cout,
                                               int M, int N, int K) {
    __shared__ __align__(16) short smem[2 * 128 * 64];   // As | Bs, reused as Lf
    short* As = smem;
    short* Bs = smem + 128 * 64;
    const int tid  = threadIdx.x;
    const int lane = tid & 63;
    const int wave = tid >> 6;

    int e, m0, n0;
    if (FUSE) {
        e = blockIdx.x & 7;                     // expert -> XCD pin
        const int r = blockIdx.x >> 3;          // 0..511
        m0 = (r & 15) << 7;                     // sweep M fastest (B-col reuse)
        n0 = (((r >> 6) << 2) + ((r >> 4) & 3)) << 7;   // col-band-of-4
    } else {
        e = blockIdx.z;
        const int gridN = gridDim.x;
        const int lin   = blockIdx.y * gridN + blockIdx.x;
        const int band  = lin / (4 * gridN);
        const int rem   = lin - band * 4 * gridN;
        m0 = (band * 4 + (rem & 3)) * 128;
        n0 = (rem >> 2) * 128;
    }
    A  += (size_t)e * M * K;
    Bt += (size_t)e * N * K;

    const int wm = (wave >> 1) * 64;            // wave sub-tile origin
    const int wn = (wave & 1) * 64;

    f32x4 acc[4][4] = {};

    const short* Ab = A  + (size_t)m0 * K;
    const short* Bb = Bt + (size_t)n0 * K;

    const int rA   = wm + (lane & 15);
    const int rB   = wn + (lane & 15);
    const int quad = lane >> 4;

    for (int k0 = 0; k0 < K; k0 += 64) {
        stage_tile64(Ab + k0, As, K, wave, lane);
        stage_tile64(Bb + k0, Bs, K, wave, lane);
        __syncthreads();

        #pragma unroll
        for (int s = 0; s < 2; ++s) {
            const int j = s * 4 + quad;         // logical 16B chunk within row
            bf16x8 af[4], bf[4];
            #pragma unroll
            for (int t = 0; t < 4; ++t) {
                const int ra = rA + t * 16;
                af[t] = *(const bf16x8*)&As[ra * 64 + ((j ^ (ra & 7)) << 3)];
            }
            #pragma unroll
            for (int t = 0; t < 4; ++t) {
                const int rb = rB + t * 16;
                bf[t] = *(const bf16x8*)&Bs[rb * 64 + ((j ^ (rb & 7)) << 3)];
            }
            #pragma unroll
            for (int i = 0; i < 4; ++i)
                #pragma unroll
                for (int jj = 0; jj < 4; ++jj)
                    acc[i][jj] = __builtin_amdgcn_mfma_f32_16x16x32_bf16(
                        af[i], bf[jj], acc[i][jj], 0, 0, 0);
        }
        __syncthreads();
    }

    // ---- epilogue via LDS roundtrip: coalesced 16B stores ----
    // acc C/D layout (m89/m91): col = lane&15, row = quad*4 + reg.
    // Pass p stages the block's n-frag p: LDS Lf[128 rows][32 cols], stride 36
    // (16B-aligned, <=2-way banks on both phases, verified by hand).
    float* Lf = (float*)smem;
    const int cL = lane & 15;
    #pragma unroll
    for (int p = 0; p < 4; ++p) {
        if (p) __syncthreads();
        #pragma unroll
        for (int i = 0; i < 4; ++i)
            #pragma unroll
            for (int r = 0; r < 4; ++r)
                Lf[(wm + i * 16 + (quad << 2) + r) * 36 + (wave & 1) * 16 + cL]
                    = acc[i][p][r];
        __syncthreads();
        #pragma unroll
        for (int c2 = 0; c2 < 2; ++c2) {
            const int id  = c2 * 256 + tid;     // 0..511
            const int row = id >> 2;            // 0..127
            const int cl  = (id & 3) * 8;       // 0,8,16,24 (local col)
            f32x4 v0 = *(const f32x4*)&Lf[row * 36 + cl];
            f32x4 v1 = *(const f32x4*)&Lf[row * 36 + cl + 4];
            const int grow = m0 + row;
            const int gcol = n0 + ((cl & 16) ? 64 : 0) + p * 16 + (cl & 8);
            if (FUSE) {
                s16x8 o;
                o[0] = f2bf(gelu_exact(v0[0])); o[1] = f2bf(gelu_exact(v0[1]));
                o[2] = f2bf(gelu_exact(v0[2])); o[3] = f2bf(gelu_exact(v0[3]));
                o[4] = f2bf(gelu_exact(v1[0])); o[5] = f2bf(gelu_exact(v1[1]));
                o[6] = f2bf(gelu_exact(v1[2])); o[7] = f2bf(gelu_exact(v1[3]));
                short* C = (short*)Cout + (size_t)e * M * N;
                *(s16x8*)&C[(size_t)grow * N + gcol] = o;
            } else {
                float* C = (float*)Cout + (size_t)e * M * N;
                *(f32x4*)&C[(size_t)grow * N + gcol]     = v0;
                *(f32x4*)&C[(size_t)grow * N + gcol + 4] = v1;
            }
        }
    }
}

// ---------- launch ----------
extern "C" void kernel_launch(void* const* d_in, const int* in_sizes, int n_in,
                              void* d_out, int out_size, void* d_ws, size_t ws_size,
                              hipStream_t stream) {
    constexpr int E = 8, Ct = 2048, H = 1024, I = 4096;   // G = 1

    const float* x  = (const float*)d_in[0];   // [1,E,Ct,H]
    const float* wi = (const float*)d_in[1];   // [E,H,I]
    const float* wo = (const float*)d_in[2];   // [E,I,H]
    float* out = (float*)d_out;                // [1,E,Ct,H] fp32

    char* ws = (char*)d_ws;
    // ws layout (bytes): xb 32MiB | wiT 64MiB | woT 64MiB | h 128MiB = 288MiB
    short* xb  = (short*)(ws);
    short* wiT = (short*)(ws + (size_t)33554432);
    short* woT = (short*)(ws + (size_t)100663296);
    short* h   = (short*)(ws + (size_t)167772160);

    // 1) merged prep: cast x, transpose+cast wi & wo
    prep<<<dim3(24576), dim3(256), 0, stream>>>(x, wi, wo, xb, wiT, woT);

    // 2) h = gelu(x @ wi):  M=Ct, N=I, K=H ; 1-D expert-pinned grid
    gemm_bt<1><<<dim3(4096), dim3(256), 0, stream>>>(
        xb, wiT, (void*)h, Ct, I, H);

    // 3) out = h @ wo:      M=Ct, N=H, K=I ; band-of-4 3-D grid
    gemm_bt<0><<<dim3(H / 128, Ct / 128, E), dim3(256), 0, stream>>>(
        h, woT, (void*)out, Ct, H, I);
}